// Round 13
// baseline (268.196 us; speedup 1.0000x reference)
//
#include <hip/hip_runtime.h>

#define DIM 128
#define NPB 32          // nodes per block in fused (4 waves x 8 nodes)
#define SCAN_CHUNK 1024 // nodes per scanA block
#define BK2_BITS 9      // 512 nodes per partition bucket
#define PART_T 16       // edges per thread in partition
#define PART_EB (256 * PART_T)  // 4096 edges per partition block

typedef unsigned int   uint32;
typedef unsigned short uint16;

__device__ __forceinline__ uint16 f32_to_bf16_rne(float f) {
    uint32 u = __float_as_uint(f);
    u += 0x7fffu + ((u >> 16) & 1u);
    return (uint16)(u >> 16);
}

// ===========================================================================
// prep: [0,64) transpose W ; [64,64+nConv) h->bf16 ; rest: per-node histogram
// ===========================================================================
__global__ __launch_bounds__(256) void prep_kernel(
    const float* __restrict__ W, float* __restrict__ Wt,
    const float* __restrict__ h, uint16* __restrict__ hb,
    const int* __restrict__ dst, int* __restrict__ cnt,
    int E, long long ND, int nConv, int doConv)
{
    const int bid = blockIdx.x;
    const int tid = threadIdx.x;
    if (bid < 64) {
        const int i = bid * 256 + tid;
        const int j = i >> 7, d = i & 127;
        Wt[d * DIM + j] = W[i];
    } else if (doConv && bid < 64 + nConv) {
        const long long base = ((long long)(bid - 64) * 256 + tid) * 8;
        if (base + 8 <= ND) {
            const float4 a = *(const float4*)&h[base];
            const float4 c = *(const float4*)&h[base + 4];
            uint4 v;
            v.x = (uint32)f32_to_bf16_rne(a.x) | ((uint32)f32_to_bf16_rne(a.y) << 16);
            v.y = (uint32)f32_to_bf16_rne(a.z) | ((uint32)f32_to_bf16_rne(a.w) << 16);
            v.z = (uint32)f32_to_bf16_rne(c.x) | ((uint32)f32_to_bf16_rne(c.y) << 16);
            v.w = (uint32)f32_to_bf16_rne(c.z) | ((uint32)f32_to_bf16_rne(c.w) << 16);
            *(uint4*)&hb[base] = v;
        }
    } else {
        const int hbase = 64 + (doConv ? nConv : 0);
        const long long e = ((long long)(bid - hbase) * 256 + tid) * 4;
        if (e + 4 <= E) {
            const int4 d4 = *(const int4*)&dst[e];
            atomicAdd(&cnt[d4.x], 1);
            atomicAdd(&cnt[d4.y], 1);
            atomicAdd(&cnt[d4.z], 1);
            atomicAdd(&cnt[d4.w], 1);
        } else {
            for (long long k = e; k < E && k < e + 4; ++k) atomicAdd(&cnt[dst[k]], 1);
        }
    }
}

// ---- scanA: per-chunk local exclusive scan + chunk totals -----------------
__global__ __launch_bounds__(256) void scanA_kernel(const int* __restrict__ cnt,
                                                    int* __restrict__ pos,
                                                    int* __restrict__ bsum, int N)
{
    __shared__ int ts[256];
    const int t = threadIdx.x;
    const int base = blockIdx.x * SCAN_CHUNK + t * 4;
    int v[4];
    int s = 0;
#pragma unroll
    for (int k = 0; k < 4; ++k) {
        v[k] = (base + k < N) ? cnt[base + k] : 0;
        s += v[k];
    }
    ts[t] = s;
    __syncthreads();
    for (int off = 1; off < 256; off <<= 1) {
        int x = (t >= off) ? ts[t - off] : 0;
        __syncthreads();
        ts[t] += x;
        __syncthreads();
    }
    int run = (t == 0) ? 0 : ts[t - 1];
    if (t == 255) bsum[blockIdx.x] = ts[255];
#pragma unroll
    for (int k = 0; k < 4; ++k) {
        if (base + k < N) pos[base + k] = run;   // LOCAL exclusive start
        run += v[k];
    }
}

// ---- scanB: excl-scan chunk totals + init bucket pointers + sentinel ------
__global__ __launch_bounds__(1024) void scanB_kernel(int* __restrict__ bsum, int nb,
                                                     const int* __restrict__ pos,
                                                     int* __restrict__ gptr,
                                                     int* __restrict__ bstart, int nbuck)
{
    __shared__ int ts[1024];
    const int t = threadIdx.x;
    ts[t] = (t < nb) ? bsum[t] : 0;
    __syncthreads();
    for (int off = 1; off < 1024; off <<= 1) {
        int x = (t >= off) ? ts[t - off] : 0;
        __syncthreads();
        ts[t] += x;
        __syncthreads();
    }
    if (t < nb) bsum[t] = (t == 0) ? 0 : ts[t - 1];   // chunk global offsets
    for (int bk = t; bk < nbuck; bk += 1024) {
        const int chunk = bk >> 1;                    // (bk<<9)>>10
        const int ec = (chunk == 0) ? 0 : ts[chunk - 1];
        const int st = ec + pos[bk << BK2_BITS];
        gptr[bk]   = st;   // mutable append pointer (partition)
        bstart[bk] = st;   // immutable copy (csrfill search)
    }
    if (t == 0) bstart[nbuck] = ts[nb - 1];           // sentinel = E
}

// ---- partition: LDS-staged radix partition; ebuf packed src|dloc<<20 ------
__global__ __launch_bounds__(256) void partition_kernel(
    const int* __restrict__ src, const int* __restrict__ dst,
    int* __restrict__ gptr, uint32* __restrict__ ebuf, int E, int nbuck)
{
    __shared__ int hist[256];     // nbuck <= 256
    const int t = threadIdx.x;
    const long long e0 = (long long)blockIdx.x * PART_EB;

    for (int i = t; i < 256; i += 256) hist[i] = 0;
    __syncthreads();

#pragma unroll 1
    for (int j = 0; j < PART_T / 4; ++j) {
        const long long be = e0 + ((long long)(j * 256 + t)) * 4;
        if (be + 4 <= E) {
            const int4 d4 = *(const int4*)&dst[be];
            atomicAdd(&hist[d4.x >> BK2_BITS], 1);
            atomicAdd(&hist[d4.y >> BK2_BITS], 1);
            atomicAdd(&hist[d4.z >> BK2_BITS], 1);
            atomicAdd(&hist[d4.w >> BK2_BITS], 1);
        } else {
            for (long long k = be; k < E && k < be + 4; ++k)
                atomicAdd(&hist[dst[k] >> BK2_BITS], 1);
        }
    }
    __syncthreads();

    for (int i = t; i < nbuck; i += 256) {
        const int c = hist[i];
        hist[i] = (c > 0) ? atomicAdd(&gptr[i], c) : 0;
    }
    __syncthreads();

#pragma unroll 1
    for (int j = 0; j < PART_T / 4; ++j) {
        const long long be = e0 + ((long long)(j * 256 + t)) * 4;
        if (be + 4 <= E) {
            const int4 s4 = *(const int4*)&src[be];
            const int4 d4 = *(const int4*)&dst[be];
            int sl;
            sl = atomicAdd(&hist[d4.x >> BK2_BITS], 1);
            ebuf[sl] = (uint32)s4.x | (((uint32)d4.x & 511u) << 20);
            sl = atomicAdd(&hist[d4.y >> BK2_BITS], 1);
            ebuf[sl] = (uint32)s4.y | (((uint32)d4.y & 511u) << 20);
            sl = atomicAdd(&hist[d4.z >> BK2_BITS], 1);
            ebuf[sl] = (uint32)s4.z | (((uint32)d4.z & 511u) << 20);
            sl = atomicAdd(&hist[d4.w >> BK2_BITS], 1);
            ebuf[sl] = (uint32)s4.w | (((uint32)d4.w & 511u) << 20);
        } else {
            for (long long k = be; k < E && k < be + 4; ++k) {
                const int d = dst[k];
                const int sl = atomicAdd(&hist[d >> BK2_BITS], 1);
                ebuf[sl] = (uint32)src[k] | (((uint32)d & 511u) << 20);
            }
        }
    }
}

// ---- csrfill: grid-parallel over ebuf; bucket found via bstart search -----
// Mutates pos to local ENDS; atomics+writes stay in each bucket's L2 window.
__global__ __launch_bounds__(256) void csrfill_kernel(
    const uint32* __restrict__ ebuf, const int* __restrict__ bstart,
    const int* __restrict__ bsum, int* __restrict__ pos,
    int* __restrict__ esrc, int E, int nbuck)
{
    __shared__ int bs[258];
    const int t = threadIdx.x;
    for (int i = t; i <= nbuck; i += 256) bs[i] = bstart[i];
    __syncthreads();
    const int i0 = blockIdx.x * 1024 + t * 4;
    if (i0 >= E) return;
    int lo = 0, hi = nbuck;                 // bs[nbuck] = E sentinel
    while (lo + 1 < hi) {
        const int mid = (lo + hi) >> 1;
        if (bs[mid] <= i0) lo = mid; else hi = mid;
    }
    int b = lo;
#pragma unroll
    for (int k = 0; k < 4; ++k) {
        const int i = i0 + k;
        if (i >= E) break;
        while (i >= bs[b + 1]) ++b;
        const uint32 p = ebuf[i];
        const int s    = (int)(p & 0xFFFFFu);
        const int dloc = (int)(p >> 20);
        const int node = (b << BK2_BITS) | dloc;
        const int slot = atomicAdd(&pos[node], 1) + bsum[node >> 10];
        esrc[slot] = s;
    }
}

// ===========================================================================
// Fused aggregate + ReLU(agg @ W^T + b).  bf16-gather, 8-deep load pipeline.
//   Gather is latency/MLP-bound (rounds 9-12): edge k is consumed while
//   loads k+8..k+15 are in flight (8 rows = 2KB outstanding per wave).
//   NOTE: #pragma unroll 1 on the d4 GEMM loop is load-bearing — full unroll
//   blows past 256 VGPRs and spills ~3.5 GB to scratch (rounds 2-3).
// ===========================================================================
__global__ __launch_bounds__(256) void fused_kernel_bf(
    const float* __restrict__ h, const uint16* __restrict__ hb,
    const int* __restrict__ cnt, const int* __restrict__ pos,
    const int* __restrict__ bsum, const int* __restrict__ esrc,
    const float* __restrict__ Wt, const float* __restrict__ bias,
    float* __restrict__ out, int N)
{
    __shared__ float row_lds[NPB][DIM];   // 16 KB

    const int lane = threadIdx.x & 63;
    const int w    = threadIdx.x >> 6;
    const int nbase = blockIdx.x * NPB + w * 8;
    const int col2 = lane * 2;
    const uint32* __restrict__ hb32 = (const uint32*)hb;   // 64 dwords/row

#define LOADK(uX, kk) { const int s_ = __shfl(e_reg, (kk), 64); \
                        uX = hb32[((uint32)s_ << 6) | (uint32)lane]; }
#define ACC(uX) { ax += __uint_as_float(uX << 16); \
                  ay += __uint_as_float(uX & 0xffff0000u); }

    // ---- Phase 1: aggregate 8 rows into LDS --------------------------------
#pragma unroll 1
    for (int i = 0; i < 8; ++i) {
        const int node = nbase + i;            // wave-uniform
        if (node >= N) break;
        const int deg = cnt[node];
        float ax, ay;
        if (deg == 0) {
            const float2 v = *(const float2*)&h[(size_t)node * DIM + col2];
            ax = v.x; ay = v.y;
        } else {
            const int start = pos[node] - deg + bsum[node >> 10];  // pos = ends
            ax = 0.f; ay = 0.f;
            int base = 0;
#pragma unroll 1
            while (base < deg) {
                const int chunk = (deg - base < 64) ? (deg - base) : 64;
                int e_reg = 0;
                if (lane < chunk) e_reg = esrc[start + base + lane];
                int k = 0;
                if (chunk >= 8) {
                    uint32 u0, u1, u2, u3, u4, u5, u6, u7;
                    LOADK(u0, 0) LOADK(u1, 1) LOADK(u2, 2) LOADK(u3, 3)
                    LOADK(u4, 4) LOADK(u5, 5) LOADK(u6, 6) LOADK(u7, 7)
#pragma unroll 1
                    for (; k + 16 <= chunk; k += 8) {
                        ACC(u0) LOADK(u0, k + 8)
                        ACC(u1) LOADK(u1, k + 9)
                        ACC(u2) LOADK(u2, k + 10)
                        ACC(u3) LOADK(u3, k + 11)
                        ACC(u4) LOADK(u4, k + 12)
                        ACC(u5) LOADK(u5, k + 13)
                        ACC(u6) LOADK(u6, k + 14)
                        ACC(u7) LOADK(u7, k + 15)
                    }
                    ACC(u0) ACC(u1) ACC(u2) ACC(u3)
                    ACC(u4) ACC(u5) ACC(u6) ACC(u7)
                    k += 8;
                }
#pragma unroll 1
                for (; k < chunk; ++k) {
                    uint32 u;
                    LOADK(u, k)
                    ACC(u)
                }
                base += chunk;
            }
            const float inv = 1.0f / (float)deg;
            ax *= inv; ay *= inv;
        }
        *(float2*)&row_lds[w * 8 + i][col2] = make_float2(ax, ay);
    }
    __syncthreads();

#undef LOADK
#undef ACC

    // ---- Phase 2: GEMM out = ReLU(row @ W^T + b) ---------------------------
    const float2 bb = *(const float2*)&bias[col2];
    float acc0[8], acc1[8];
#pragma unroll
    for (int n = 0; n < 8; ++n) { acc0[n] = bb.x; acc1[n] = bb.y; }

#pragma unroll 1
    for (int d4 = 0; d4 < DIM; d4 += 4) {
        float4 a[8];
#pragma unroll
        for (int n = 0; n < 8; ++n)
            a[n] = *(const float4*)&row_lds[w * 8 + n][d4];   // broadcast
#pragma unroll
        for (int dd = 0; dd < 4; ++dd) {
            const float2 wt = *(const float2*)&Wt[(d4 + dd) * DIM + col2];
#pragma unroll
            for (int n = 0; n < 8; ++n) {
                const float av = dd == 0 ? a[n].x : dd == 1 ? a[n].y
                               : dd == 2 ? a[n].z : a[n].w;
                acc0[n] = fmaf(av, wt.x, acc0[n]);
                acc1[n] = fmaf(av, wt.y, acc1[n]);
            }
        }
    }

#pragma unroll
    for (int n = 0; n < 8; ++n) {
        const int node = nbase + n;
        if (node < N) {
            *(float2*)&out[(size_t)node * DIM + col2] =
                make_float2(fmaxf(acc0[n], 0.0f), fmaxf(acc1[n], 0.0f));
        }
    }
}

// ===========================================================================
// Fallback path (ws too small): direct fill + f32 CSR gather.
// ===========================================================================
__global__ __launch_bounds__(256) void fill_direct_kernel(
    const int* __restrict__ src, const int* __restrict__ dst,
    int* __restrict__ pos, const int* __restrict__ bsum,
    int* __restrict__ esrc, int E)
{
    const long long e = ((long long)blockIdx.x * 256 + threadIdx.x) * 4;
    if (e + 4 <= E) {
        const int4 s4 = *(const int4*)&src[e];
        const int4 d4 = *(const int4*)&dst[e];
        int sl;
        sl = atomicAdd(&pos[d4.x], 1); esrc[sl + bsum[d4.x >> 10]] = s4.x;
        sl = atomicAdd(&pos[d4.y], 1); esrc[sl + bsum[d4.y >> 10]] = s4.y;
        sl = atomicAdd(&pos[d4.z], 1); esrc[sl + bsum[d4.z >> 10]] = s4.z;
        sl = atomicAdd(&pos[d4.w], 1); esrc[sl + bsum[d4.w >> 10]] = s4.w;
    } else {
        for (long long k = e; k < E && k < e + 4; ++k) {
            const int d = dst[k];
            const int sl = atomicAdd(&pos[d], 1);
            esrc[sl + bsum[d >> 10]] = src[k];
        }
    }
}

__global__ __launch_bounds__(256) void fused_kernel_f32(
    const float* __restrict__ h,
    const int* __restrict__ cnt, const int* __restrict__ pos,
    const int* __restrict__ bsum, const int* __restrict__ esrc,
    const float* __restrict__ Wt, const float* __restrict__ bias,
    float* __restrict__ out, int N)
{
    __shared__ float row_lds[NPB][DIM];
    const int lane = threadIdx.x & 63;
    const int w    = threadIdx.x >> 6;
    const int nbase = blockIdx.x * NPB + w * 8;
    const int col2 = lane * 2;

#pragma unroll 1
    for (int i = 0; i < 8; ++i) {
        const int node = nbase + i;
        if (node >= N) break;
        const int deg = cnt[node];
        float ax, ay;
        if (deg == 0) {
            const float2 v = *(const float2*)&h[(size_t)node * DIM + col2];
            ax = v.x; ay = v.y;
        } else {
            const int start = pos[node] - deg + bsum[node >> 10];
            ax = 0.f; ay = 0.f;
#pragma unroll 4
            for (int k = 0; k < deg; ++k) {
                const int s = esrc[start + k];
                const float2 v = *(const float2*)&h[(size_t)s * DIM + col2];
                ax += v.x; ay += v.y;
            }
            const float inv = 1.0f / (float)deg;
            ax *= inv; ay *= inv;
        }
        *(float2*)&row_lds[w * 8 + i][col2] = make_float2(ax, ay);
    }
    __syncthreads();

    const float2 bb = *(const float2*)&bias[col2];
    float acc0[8], acc1[8];
#pragma unroll
    for (int n = 0; n < 8; ++n) { acc0[n] = bb.x; acc1[n] = bb.y; }

#pragma unroll 1
    for (int d4 = 0; d4 < DIM; d4 += 4) {
        float4 a[8];
#pragma unroll
        for (int n = 0; n < 8; ++n)
            a[n] = *(const float4*)&row_lds[w * 8 + n][d4];
#pragma unroll
        for (int dd = 0; dd < 4; ++dd) {
            const float2 wt = *(const float2*)&Wt[(d4 + dd) * DIM + col2];
#pragma unroll
            for (int n = 0; n < 8; ++n) {
                const float av = dd == 0 ? a[n].x : dd == 1 ? a[n].y
                               : dd == 2 ? a[n].z : a[n].w;
                acc0[n] = fmaf(av, wt.x, acc0[n]);
                acc1[n] = fmaf(av, wt.y, acc1[n]);
            }
        }
    }

#pragma unroll
    for (int n = 0; n < 8; ++n) {
        const int node = nbase + n;
        if (node < N) {
            *(float2*)&out[(size_t)node * DIM + col2] =
                make_float2(fmaxf(acc0[n], 0.0f), fmaxf(acc1[n], 0.0f));
        }
    }
}

// ===========================================================================
extern "C" void kernel_launch(void* const* d_in, const int* in_sizes, int n_in,
                              void* d_out, int out_size, void* d_ws, size_t ws_size,
                              hipStream_t stream)
{
    const float* h  = (const float*)d_in[0];
    const int* src  = (const int*)d_in[1];
    const int* dst  = (const int*)d_in[2];
    const float* W  = (const float*)d_in[3];
    const float* b  = (const float*)d_in[4];
    float* out = (float*)d_out;

    const int N = in_sizes[0] / DIM;
    const int E = in_sizes[1];
    const long long ND = (long long)N * DIM;
    const int nb = (N + SCAN_CHUNK - 1) / SCAN_CHUNK;
    const int nbuck = (N + (1 << BK2_BITS) - 1) >> BK2_BITS;

    // Workspace layout
    const size_t off_cnt  = 0;
    const size_t off_pos  = (size_t)N * sizeof(int);
    const size_t off_esrc = off_pos + (size_t)N * sizeof(int);
    const size_t off_wt   = off_esrc + (size_t)E * sizeof(int);
    const size_t off_bsum = off_wt + (size_t)DIM * DIM * sizeof(float);
    const size_t off_gp   = off_bsum + 4096;
    const size_t off_bs2  = off_gp + 1024;
    const size_t off_hb   = (off_bs2 + 2048 + 255) & ~(size_t)255;
    const size_t off_ebuf = (off_hb + (size_t)ND * sizeof(uint16) + 255) & ~(size_t)255;
    const size_t req_bf   = off_ebuf;                                   // hb only
    const size_t req_full = off_ebuf + (size_t)E * sizeof(uint32);      // + packed ebuf

    int*    cnt    = (int*)((char*)d_ws + off_cnt);
    int*    pos    = (int*)((char*)d_ws + off_pos);
    int*    esrc   = (int*)((char*)d_ws + off_esrc);
    float*  Wt     = (float*)((char*)d_ws + off_wt);
    int*    bsum   = (int*)((char*)d_ws + off_bsum);
    int*    gptr   = (int*)((char*)d_ws + off_gp);
    int*    bstart = (int*)((char*)d_ws + off_bs2);
    uint16* hb     = (uint16*)((char*)d_ws + off_hb);
    uint32* ebuf   = (uint32*)((char*)d_ws + off_ebuf);

    const int packOK   = (N <= (1 << 20)) && (nbuck <= 256);
    const int doConv   = (ws_size >= req_bf) ? 1 : 0;
    const int doBucket = (ws_size >= req_full && packOK && doConv) ? 1 : 0;
    const int nConv  = (int)((ND / 8 + 255) / 256);
    const int nEdgeB = (int)(((long long)E / 4 + 255) / 256) + 1;
    const int nPrep  = 64 + (doConv ? nConv : 0) + nEdgeB;
    const int nPart  = (int)(((long long)E + PART_EB - 1) / PART_EB);
    const int nFill  = (int)(((long long)E + 1023) / 1024);

    hipMemsetAsync(cnt, 0, (size_t)N * sizeof(int), stream);
    prep_kernel<<<nPrep, 256, 0, stream>>>(W, Wt, h, hb, dst, cnt, E, ND, nConv, doConv);
    scanA_kernel<<<nb, 256, 0, stream>>>(cnt, pos, bsum, N);
    scanB_kernel<<<1, 1024, 0, stream>>>(bsum, nb, pos, gptr, bstart, nbuck);

    if (doBucket) {
        partition_kernel<<<nPart, 256, 0, stream>>>(src, dst, gptr, ebuf, E, nbuck);
        csrfill_kernel<<<nFill, 256, 0, stream>>>(ebuf, bstart, bsum, pos, esrc, E, nbuck);
        fused_kernel_bf<<<(N + NPB - 1) / NPB, 256, 0, stream>>>(h, hb, cnt, pos, bsum, esrc, Wt, b, out, N);
    } else {
        fill_direct_kernel<<<nEdgeB, 256, 0, stream>>>(src, dst, pos, bsum, esrc, E);
        fused_kernel_f32<<<(N + NPB - 1) / NPB, 256, 0, stream>>>(h, cnt, pos, bsum, esrc, Wt, b, out, N);
    }
}

// Round 14
// 178.226 us; speedup vs baseline: 1.5048x; 1.5048x over previous
//
#include <hip/hip_runtime.h>

#define DIM 128
#define NPB 32          // nodes per block in fused (4 waves x 8 nodes)
#define SCAN_CHUNK 1024 // nodes per scanA block (fallback only)
#define BK2_BITS 9      // 512 nodes per bucket
#define PART_T 32       // edges per thread in partition
#define PART_EB (256 * PART_T)  // 8192 edges per partition block
#define PH_T 16         // edges per thread in prep hist
#define PH_EB (256 * PH_T)

typedef unsigned int   uint32;
typedef unsigned short uint16;

__device__ __forceinline__ uint16 f32_to_bf16_rne(float f) {
    uint32 u = __float_as_uint(f);
    u += 0x7fffu + ((u >> 16) & 1u);
    return (uint16)(u >> 16);
}

// ===========================================================================
// prep2: [0,64) transpose W ; [64,64+nConv) h->bf16 ; rest: histogram.
//   bucketMode=1: LDS-staged BUCKET histogram (196 counters -> bcnt).
//   bucketMode=0 (fallback): per-node global atomics into cnt.
// ===========================================================================
__global__ __launch_bounds__(256) void prep2_kernel(
    const float* __restrict__ W, float* __restrict__ Wt,
    const float* __restrict__ h, uint16* __restrict__ hb,
    const int* __restrict__ dst, int* __restrict__ cntOrB,
    int E, long long ND, int nConv, int doConv, int bucketMode)
{
    __shared__ int hist[256];
    const int bid = blockIdx.x;
    const int tid = threadIdx.x;
    if (bid < 64) {
        const int i = bid * 256 + tid;
        const int j = i >> 7, d = i & 127;
        Wt[d * DIM + j] = W[i];
    } else if (doConv && bid < 64 + nConv) {
        const long long base = ((long long)(bid - 64) * 256 + tid) * 8;
        if (base + 8 <= ND) {
            const float4 a = *(const float4*)&h[base];
            const float4 c = *(const float4*)&h[base + 4];
            uint4 v;
            v.x = (uint32)f32_to_bf16_rne(a.x) | ((uint32)f32_to_bf16_rne(a.y) << 16);
            v.y = (uint32)f32_to_bf16_rne(a.z) | ((uint32)f32_to_bf16_rne(a.w) << 16);
            v.z = (uint32)f32_to_bf16_rne(c.x) | ((uint32)f32_to_bf16_rne(c.y) << 16);
            v.w = (uint32)f32_to_bf16_rne(c.z) | ((uint32)f32_to_bf16_rne(c.w) << 16);
            *(uint4*)&hb[base] = v;
        }
    } else {
        const int hbase = 64 + (doConv ? nConv : 0);
        const long long e0 = (long long)(bid - hbase) * PH_EB;
        if (bucketMode) {
            hist[tid] = 0;
            __syncthreads();
#pragma unroll 1
            for (int j = 0; j < PH_T / 4; ++j) {
                const long long be = e0 + ((long long)(j * 256 + tid)) * 4;
                if (be + 4 <= E) {
                    const int4 d4 = *(const int4*)&dst[be];
                    atomicAdd(&hist[d4.x >> BK2_BITS], 1);
                    atomicAdd(&hist[d4.y >> BK2_BITS], 1);
                    atomicAdd(&hist[d4.z >> BK2_BITS], 1);
                    atomicAdd(&hist[d4.w >> BK2_BITS], 1);
                } else {
                    for (long long k = be; k < E && k < be + 4; ++k)
                        atomicAdd(&hist[dst[k] >> BK2_BITS], 1);
                }
            }
            __syncthreads();
            const int c = hist[tid];
            if (c > 0) atomicAdd(&cntOrB[tid], c);
        } else {
#pragma unroll 1
            for (int j = 0; j < PH_T / 4; ++j) {
                const long long be = e0 + ((long long)(j * 256 + tid)) * 4;
                if (be + 4 <= E) {
                    const int4 d4 = *(const int4*)&dst[be];
                    atomicAdd(&cntOrB[d4.x], 1);
                    atomicAdd(&cntOrB[d4.y], 1);
                    atomicAdd(&cntOrB[d4.z], 1);
                    atomicAdd(&cntOrB[d4.w], 1);
                } else {
                    for (long long k = be; k < E && k < be + 4; ++k)
                        atomicAdd(&cntOrB[dst[k]], 1);
                }
            }
        }
    }
}

// ---- bscan: 1 block; exclusive scan of bucket counts -> bstart, gptr ------
__global__ __launch_bounds__(256) void bscan_kernel(
    const int* __restrict__ bcnt, int* __restrict__ bstart,
    int* __restrict__ gptr, int nbuck, int E)
{
    __shared__ int ts[256];
    const int t = threadIdx.x;
    ts[t] = (t < nbuck) ? bcnt[t] : 0;
    __syncthreads();
    for (int off = 1; off < 256; off <<= 1) {
        int x = (t >= off) ? ts[t - off] : 0;
        __syncthreads();
        ts[t] += x;
        __syncthreads();
    }
    const int ex = (t == 0) ? 0 : ts[t - 1];
    if (t < nbuck) { bstart[t] = ex; gptr[t] = ex; }
    if (t == 0) bstart[nbuck] = E;   // sentinel
}

// ---- partition: LDS-staged radix partition; ebuf packed src|dloc<<20 ------
__global__ __launch_bounds__(256) void partition_kernel(
    const int* __restrict__ src, const int* __restrict__ dst,
    int* __restrict__ gptr, uint32* __restrict__ ebuf, int E, int nbuck)
{
    __shared__ int hist[256];
    const int t = threadIdx.x;
    const long long e0 = (long long)blockIdx.x * PART_EB;

    hist[t] = 0;
    __syncthreads();

#pragma unroll 1
    for (int j = 0; j < PART_T / 4; ++j) {
        const long long be = e0 + ((long long)(j * 256 + t)) * 4;
        if (be + 4 <= E) {
            const int4 d4 = *(const int4*)&dst[be];
            atomicAdd(&hist[d4.x >> BK2_BITS], 1);
            atomicAdd(&hist[d4.y >> BK2_BITS], 1);
            atomicAdd(&hist[d4.z >> BK2_BITS], 1);
            atomicAdd(&hist[d4.w >> BK2_BITS], 1);
        } else {
            for (long long k = be; k < E && k < be + 4; ++k)
                atomicAdd(&hist[dst[k] >> BK2_BITS], 1);
        }
    }
    __syncthreads();

    for (int i = t; i < nbuck; i += 256) {
        const int c = hist[i];
        hist[i] = (c > 0) ? atomicAdd(&gptr[i], c) : 0;
    }
    __syncthreads();

#pragma unroll 1
    for (int j = 0; j < PART_T / 4; ++j) {
        const long long be = e0 + ((long long)(j * 256 + t)) * 4;
        if (be + 4 <= E) {
            const int4 s4 = *(const int4*)&src[be];
            const int4 d4 = *(const int4*)&dst[be];
            int sl;
            sl = atomicAdd(&hist[d4.x >> BK2_BITS], 1);
            ebuf[sl] = (uint32)s4.x | (((uint32)d4.x & 511u) << 20);
            sl = atomicAdd(&hist[d4.y >> BK2_BITS], 1);
            ebuf[sl] = (uint32)s4.y | (((uint32)d4.y & 511u) << 20);
            sl = atomicAdd(&hist[d4.z >> BK2_BITS], 1);
            ebuf[sl] = (uint32)s4.z | (((uint32)d4.z & 511u) << 20);
            sl = atomicAdd(&hist[d4.w >> BK2_BITS], 1);
            ebuf[sl] = (uint32)s4.w | (((uint32)d4.w & 511u) << 20);
        } else {
            for (long long k = be; k < E && k < be + 4; ++k) {
                const int d = dst[k];
                const int sl = atomicAdd(&hist[d >> BK2_BITS], 1);
                ebuf[sl] = (uint32)src[k] | (((uint32)d & 511u) << 20);
            }
        }
    }
}

// ---- csrfill2: one block per bucket. LDS node-count + LDS scan derive the
// per-node CSR offsets (replaces memset-cnt, prep per-node hist, scanA/B),
// then fill esrc. Writes cnt[] and pos[] (= GLOBAL starts) for fused.
// ===========================================================================
__global__ __launch_bounds__(256) void csrfill2_kernel(
    const uint32* __restrict__ ebuf, const int* __restrict__ bstart,
    int* __restrict__ pos, int* __restrict__ cnt,
    int* __restrict__ esrc, int N)
{
    __shared__ int lcnt[512];
    __shared__ int lpos[512];
    __shared__ int ts[256];
    const int b = blockIdx.x;
    const int t = threadIdx.x;
    const int seg0 = bstart[b], seg1 = bstart[b + 1];
    lcnt[t] = 0; lcnt[t + 256] = 0;
    __syncthreads();
    for (int i = seg0 + t; i < seg1; i += 256)
        atomicAdd(&lcnt[ebuf[i] >> 20], 1);
    __syncthreads();
    const int a0 = lcnt[2 * t], a1 = lcnt[2 * t + 1];
    ts[t] = a0 + a1;
    __syncthreads();
    for (int off = 1; off < 256; off <<= 1) {
        int x = (t >= off) ? ts[t - off] : 0;
        __syncthreads();
        ts[t] += x;
        __syncthreads();
    }
    const int pb = (t == 0) ? 0 : ts[t - 1];
    const int s0 = seg0 + pb, s1 = seg0 + pb + a0;
    lpos[2 * t] = s0; lpos[2 * t + 1] = s1;
    const int n0 = (b << BK2_BITS) + 2 * t;
    if (n0 < N)     { pos[n0] = s0;     cnt[n0] = a0; }
    if (n0 + 1 < N) { pos[n0 + 1] = s1; cnt[n0 + 1] = a1; }
    __syncthreads();
    for (int i = seg0 + t; i < seg1; i += 256) {
        const uint32 p = ebuf[i];
        const int slot = atomicAdd(&lpos[p >> 20], 1);
        esrc[slot] = (int)(p & 0xFFFFFu);
    }
}

// ===========================================================================
// Fused aggregate + ReLU(agg @ W^T + b).  bf16-gather, 4-deep load pipeline
// (round 12: 119us; 8-deep was null -> at random-row service floor).
//   NOTE: #pragma unroll 1 on the d4 GEMM loop is load-bearing — full unroll
//   blows past 256 VGPRs and spills ~3.5 GB to scratch (rounds 2-3).
// ===========================================================================
__global__ __launch_bounds__(256) void fused_kernel_bf(
    const float* __restrict__ h, const uint16* __restrict__ hb,
    const int* __restrict__ cnt, const int* __restrict__ pos,
    const int* __restrict__ esrc,
    const float* __restrict__ Wt, const float* __restrict__ bias,
    float* __restrict__ out, int N)
{
    __shared__ float row_lds[NPB][DIM];   // 16 KB

    const int lane = threadIdx.x & 63;
    const int w    = threadIdx.x >> 6;
    const int nbase = blockIdx.x * NPB + w * 8;
    const int col2 = lane * 2;
    const uint32* __restrict__ hb32 = (const uint32*)hb;   // 64 dwords/row

#define LOADK(uX, kk) { const int s_ = __shfl(e_reg, (kk), 64); \
                        uX = hb32[((uint32)s_ << 6) | (uint32)lane]; }
#define ACC(uX) { ax += __uint_as_float(uX << 16); \
                  ay += __uint_as_float(uX & 0xffff0000u); }

#pragma unroll 1
    for (int i = 0; i < 8; ++i) {
        const int node = nbase + i;            // wave-uniform
        if (node >= N) break;
        const int deg = cnt[node];
        float ax, ay;
        if (deg == 0) {
            const float2 v = *(const float2*)&h[(size_t)node * DIM + col2];
            ax = v.x; ay = v.y;
        } else {
            const int start = pos[node];       // pos = global starts
            ax = 0.f; ay = 0.f;
            int base = 0;
#pragma unroll 1
            while (base < deg) {
                const int chunk = (deg - base < 64) ? (deg - base) : 64;
                int e_reg = 0;
                if (lane < chunk) e_reg = esrc[start + base + lane];
                int k = 0;
                if (chunk >= 4) {
                    uint32 u0, u1, u2, u3;
                    LOADK(u0, 0) LOADK(u1, 1) LOADK(u2, 2) LOADK(u3, 3)
#pragma unroll 1
                    for (; k + 8 <= chunk; k += 4) {
                        ACC(u0) LOADK(u0, k + 4)
                        ACC(u1) LOADK(u1, k + 5)
                        ACC(u2) LOADK(u2, k + 6)
                        ACC(u3) LOADK(u3, k + 7)
                    }
                    ACC(u0) ACC(u1) ACC(u2) ACC(u3)
                    k += 4;
                }
#pragma unroll 1
                for (; k < chunk; ++k) {
                    uint32 u;
                    LOADK(u, k)
                    ACC(u)
                }
                base += chunk;
            }
            const float inv = 1.0f / (float)deg;
            ax *= inv; ay *= inv;
        }
        *(float2*)&row_lds[w * 8 + i][col2] = make_float2(ax, ay);
    }
    __syncthreads();

#undef LOADK
#undef ACC

    const float2 bb = *(const float2*)&bias[col2];
    float acc0[8], acc1[8];
#pragma unroll
    for (int n = 0; n < 8; ++n) { acc0[n] = bb.x; acc1[n] = bb.y; }

#pragma unroll 1
    for (int d4 = 0; d4 < DIM; d4 += 4) {
        float4 a[8];
#pragma unroll
        for (int n = 0; n < 8; ++n)
            a[n] = *(const float4*)&row_lds[w * 8 + n][d4];   // broadcast
#pragma unroll
        for (int dd = 0; dd < 4; ++dd) {
            const float2 wt = *(const float2*)&Wt[(d4 + dd) * DIM + col2];
#pragma unroll
            for (int n = 0; n < 8; ++n) {
                const float av = dd == 0 ? a[n].x : dd == 1 ? a[n].y
                               : dd == 2 ? a[n].z : a[n].w;
                acc0[n] = fmaf(av, wt.x, acc0[n]);
                acc1[n] = fmaf(av, wt.y, acc1[n]);
            }
        }
    }

#pragma unroll
    for (int n = 0; n < 8; ++n) {
        const int node = nbase + n;
        if (node < N) {
            *(float2*)&out[(size_t)node * DIM + col2] =
                make_float2(fmaxf(acc0[n], 0.0f), fmaxf(acc1[n], 0.0f));
        }
    }
}

// ===========================================================================
// Fallback path (ws too small): per-node hist + scanA/B + direct fill + f32.
// ===========================================================================
__global__ __launch_bounds__(256) void scanA_kernel(const int* __restrict__ cnt,
                                                    int* __restrict__ pos,
                                                    int* __restrict__ bsum, int N)
{
    __shared__ int ts[256];
    const int t = threadIdx.x;
    const int base = blockIdx.x * SCAN_CHUNK + t * 4;
    int v[4];
    int s = 0;
#pragma unroll
    for (int k = 0; k < 4; ++k) {
        v[k] = (base + k < N) ? cnt[base + k] : 0;
        s += v[k];
    }
    ts[t] = s;
    __syncthreads();
    for (int off = 1; off < 256; off <<= 1) {
        int x = (t >= off) ? ts[t - off] : 0;
        __syncthreads();
        ts[t] += x;
        __syncthreads();
    }
    int run = (t == 0) ? 0 : ts[t - 1];
    if (t == 255) bsum[blockIdx.x] = ts[255];
#pragma unroll
    for (int k = 0; k < 4; ++k) {
        if (base + k < N) pos[base + k] = run;
        run += v[k];
    }
}

__global__ __launch_bounds__(1024) void scanB_fb_kernel(int* __restrict__ bsum, int nb)
{
    __shared__ int ts[1024];
    const int t = threadIdx.x;
    ts[t] = (t < nb) ? bsum[t] : 0;
    __syncthreads();
    for (int off = 1; off < 1024; off <<= 1) {
        int x = (t >= off) ? ts[t - off] : 0;
        __syncthreads();
        ts[t] += x;
        __syncthreads();
    }
    if (t < nb) bsum[t] = (t == 0) ? 0 : ts[t - 1];
}

__global__ __launch_bounds__(256) void fill_direct_kernel(
    const int* __restrict__ src, const int* __restrict__ dst,
    int* __restrict__ pos, const int* __restrict__ bsum,
    int* __restrict__ esrc, int E)
{
    const long long e = ((long long)blockIdx.x * 256 + threadIdx.x) * 4;
    if (e + 4 <= E) {
        const int4 s4 = *(const int4*)&src[e];
        const int4 d4 = *(const int4*)&dst[e];
        int sl;
        sl = atomicAdd(&pos[d4.x], 1); esrc[sl + bsum[d4.x >> 10]] = s4.x;
        sl = atomicAdd(&pos[d4.y], 1); esrc[sl + bsum[d4.y >> 10]] = s4.y;
        sl = atomicAdd(&pos[d4.z], 1); esrc[sl + bsum[d4.z >> 10]] = s4.z;
        sl = atomicAdd(&pos[d4.w], 1); esrc[sl + bsum[d4.w >> 10]] = s4.w;
    } else {
        for (long long k = e; k < E && k < e + 4; ++k) {
            const int d = dst[k];
            const int sl = atomicAdd(&pos[d], 1);
            esrc[sl + bsum[d >> 10]] = src[k];
        }
    }
}

__global__ __launch_bounds__(256) void fused_kernel_f32(
    const float* __restrict__ h,
    const int* __restrict__ cnt, const int* __restrict__ pos,
    const int* __restrict__ bsum, const int* __restrict__ esrc,
    const float* __restrict__ Wt, const float* __restrict__ bias,
    float* __restrict__ out, int N)
{
    __shared__ float row_lds[NPB][DIM];
    const int lane = threadIdx.x & 63;
    const int w    = threadIdx.x >> 6;
    const int nbase = blockIdx.x * NPB + w * 8;
    const int col2 = lane * 2;

#pragma unroll 1
    for (int i = 0; i < 8; ++i) {
        const int node = nbase + i;
        if (node >= N) break;
        const int deg = cnt[node];
        float ax, ay;
        if (deg == 0) {
            const float2 v = *(const float2*)&h[(size_t)node * DIM + col2];
            ax = v.x; ay = v.y;
        } else {
            const int start = pos[node] - deg + bsum[node >> 10];
            ax = 0.f; ay = 0.f;
#pragma unroll 4
            for (int k = 0; k < deg; ++k) {
                const int s = esrc[start + k];
                const float2 v = *(const float2*)&h[(size_t)s * DIM + col2];
                ax += v.x; ay += v.y;
            }
            const float inv = 1.0f / (float)deg;
            ax *= inv; ay *= inv;
        }
        *(float2*)&row_lds[w * 8 + i][col2] = make_float2(ax, ay);
    }
    __syncthreads();

    const float2 bb = *(const float2*)&bias[col2];
    float acc0[8], acc1[8];
#pragma unroll
    for (int n = 0; n < 8; ++n) { acc0[n] = bb.x; acc1[n] = bb.y; }

#pragma unroll 1
    for (int d4 = 0; d4 < DIM; d4 += 4) {
        float4 a[8];
#pragma unroll
        for (int n = 0; n < 8; ++n)
            a[n] = *(const float4*)&row_lds[w * 8 + n][d4];
#pragma unroll
        for (int dd = 0; dd < 4; ++dd) {
            const float2 wt = *(const float2*)&Wt[(d4 + dd) * DIM + col2];
#pragma unroll
            for (int n = 0; n < 8; ++n) {
                const float av = dd == 0 ? a[n].x : dd == 1 ? a[n].y
                               : dd == 2 ? a[n].z : a[n].w;
                acc0[n] = fmaf(av, wt.x, acc0[n]);
                acc1[n] = fmaf(av, wt.y, acc1[n]);
            }
        }
    }

#pragma unroll
    for (int n = 0; n < 8; ++n) {
        const int node = nbase + n;
        if (node < N) {
            *(float2*)&out[(size_t)node * DIM + col2] =
                make_float2(fmaxf(acc0[n], 0.0f), fmaxf(acc1[n], 0.0f));
        }
    }
}

// ===========================================================================
extern "C" void kernel_launch(void* const* d_in, const int* in_sizes, int n_in,
                              void* d_out, int out_size, void* d_ws, size_t ws_size,
                              hipStream_t stream)
{
    const float* h  = (const float*)d_in[0];
    const int* src  = (const int*)d_in[1];
    const int* dst  = (const int*)d_in[2];
    const float* W  = (const float*)d_in[3];
    const float* b  = (const float*)d_in[4];
    float* out = (float*)d_out;

    const int N = in_sizes[0] / DIM;
    const int E = in_sizes[1];
    const long long ND = (long long)N * DIM;
    const int nbuck = (N + (1 << BK2_BITS) - 1) >> BK2_BITS;

    // Workspace layout
    const size_t off_cnt  = 0;
    const size_t off_pos  = (size_t)N * sizeof(int);
    const size_t off_esrc = off_pos + (size_t)N * sizeof(int);
    const size_t off_wt   = off_esrc + (size_t)E * sizeof(int);
    const size_t off_bcnt = off_wt + (size_t)DIM * DIM * sizeof(float);
    const size_t off_bst  = off_bcnt + 1024;
    const size_t off_gp   = off_bst + 1040;
    const size_t off_bsum = off_gp + 1024;
    const size_t off_hb   = (off_bsum + 4096 + 255) & ~(size_t)255;
    const size_t off_ebuf = (off_hb + (size_t)ND * sizeof(uint16) + 255) & ~(size_t)255;
    const size_t req_fb   = off_hb;
    const size_t req_full = off_ebuf + (size_t)E * sizeof(uint32);

    int*    cnt    = (int*)((char*)d_ws + off_cnt);
    int*    pos    = (int*)((char*)d_ws + off_pos);
    int*    esrc   = (int*)((char*)d_ws + off_esrc);
    float*  Wt     = (float*)((char*)d_ws + off_wt);
    int*    bcnt   = (int*)((char*)d_ws + off_bcnt);
    int*    bstart = (int*)((char*)d_ws + off_bst);
    int*    gptr   = (int*)((char*)d_ws + off_gp);
    int*    bsum   = (int*)((char*)d_ws + off_bsum);
    uint16* hb     = (uint16*)((char*)d_ws + off_hb);
    uint32* ebuf   = (uint32*)((char*)d_ws + off_ebuf);

    const int packOK   = (N <= (1 << 20)) && (nbuck <= 256);
    const int doBucket = (ws_size >= req_full && packOK) ? 1 : 0;
    const int nConv  = (int)((ND / 8 + 255) / 256);
    const int nHist  = (int)(((long long)E + PH_EB - 1) / PH_EB);
    const int nPart  = (int)(((long long)E + PART_EB - 1) / PART_EB);

    if (doBucket) {
        const int nPrep = 64 + nConv + nHist;
        hipMemsetAsync(bcnt, 0, 1024, stream);
        prep2_kernel<<<nPrep, 256, 0, stream>>>(W, Wt, h, hb, dst, bcnt, E, ND, nConv, 1, 1);
        bscan_kernel<<<1, 256, 0, stream>>>(bcnt, bstart, gptr, nbuck, E);
        partition_kernel<<<nPart, 256, 0, stream>>>(src, dst, gptr, ebuf, E, nbuck);
        csrfill2_kernel<<<nbuck, 256, 0, stream>>>(ebuf, bstart, pos, cnt, esrc, N);
        fused_kernel_bf<<<(N + NPB - 1) / NPB, 256, 0, stream>>>(h, hb, cnt, pos, esrc, Wt, b, out, N);
    } else {
        const int nb = (N + SCAN_CHUNK - 1) / SCAN_CHUNK;
        const int nPrep = 64 + nHist;
        const int nEdgeB = (int)(((long long)E / 4 + 255) / 256) + 1;
        hipMemsetAsync(cnt, 0, (size_t)N * sizeof(int), stream);
        prep2_kernel<<<nPrep, 256, 0, stream>>>(W, Wt, h, hb, dst, cnt, E, ND, nConv, 0, 0);
        scanA_kernel<<<nb, 256, 0, stream>>>(cnt, pos, bsum, N);
        scanB_fb_kernel<<<1, 1024, 0, stream>>>(bsum, nb);
        fill_direct_kernel<<<nEdgeB, 256, 0, stream>>>(src, dst, pos, bsum, esrc, E);
        fused_kernel_f32<<<(N + NPB - 1) / NPB, 256, 0, stream>>>(h, cnt, pos, bsum, esrc, Wt, b, out, N);
    }
}

// Round 15
// 176.806 us; speedup vs baseline: 1.5169x; 1.0080x over previous
//
#include <hip/hip_runtime.h>

#define DIM 128
#define NPB 32          // nodes per block in fused (4 waves x 8 nodes)
#define SCAN_CHUNK 1024 // nodes per scanA block (fallback only)
#define BK2_BITS 9      // 512 nodes per bucket
#define PART_T 32       // edges per thread in partition
#define PART_EB (256 * PART_T)  // 8192 edges per partition block
#define PH_T 16
#define PH_EB (256 * PH_T)

typedef unsigned int   uint32;
typedef unsigned short uint16;

__device__ __forceinline__ uint16 f32_to_bf16_rne(float f) {
    uint32 u = __float_as_uint(f);
    u += 0x7fffu + ((u >> 16) & 1u);
    return (uint16)(u >> 16);
}

// ---- init: padded bucket append pointers gptr[b] = b*C --------------------
__global__ __launch_bounds__(256) void init_kernel(int* __restrict__ gptr,
                                                   int nbuck, int C)
{
    const int t = threadIdx.x;
    if (t < nbuck) gptr[t] = t * C;
}

// ===========================================================================
// partition2: [0,64) transpose W ; [64,64+nConv) h->bf16 ;
//             rest: LDS-staged radix partition into PADDED buckets.
// Packed edge word: src (bits 0..19) | dstLocal (bits 20..28).
// ===========================================================================
__global__ __launch_bounds__(256) void partition2_kernel(
    const float* __restrict__ W, float* __restrict__ Wt,
    const float* __restrict__ h, uint16* __restrict__ hb,
    const int* __restrict__ src, const int* __restrict__ dst,
    int* __restrict__ gptr, uint32* __restrict__ ebuf,
    int E, long long ND, int nConv, int nbuck)
{
    __shared__ int hist[256];
    const int bid = blockIdx.x;
    const int t = threadIdx.x;

    if (bid < 64) {
        const int i = bid * 256 + t;
        const int j = i >> 7, d = i & 127;
        Wt[d * DIM + j] = W[i];
        return;
    }
    if (bid < 64 + nConv) {
        const long long base = ((long long)(bid - 64) * 256 + t) * 8;
        if (base + 8 <= ND) {
            const float4 a = *(const float4*)&h[base];
            const float4 c = *(const float4*)&h[base + 4];
            uint4 v;
            v.x = (uint32)f32_to_bf16_rne(a.x) | ((uint32)f32_to_bf16_rne(a.y) << 16);
            v.y = (uint32)f32_to_bf16_rne(a.z) | ((uint32)f32_to_bf16_rne(a.w) << 16);
            v.z = (uint32)f32_to_bf16_rne(c.x) | ((uint32)f32_to_bf16_rne(c.y) << 16);
            v.w = (uint32)f32_to_bf16_rne(c.z) | ((uint32)f32_to_bf16_rne(c.w) << 16);
            *(uint4*)&hb[base] = v;
        }
        return;
    }

    const long long e0 = (long long)(bid - 64 - nConv) * PART_EB;
    hist[t] = 0;
    __syncthreads();

    // step 1: block-local bucket histogram
#pragma unroll 1
    for (int j = 0; j < PART_T / 4; ++j) {
        const long long be = e0 + ((long long)(j * 256 + t)) * 4;
        if (be + 4 <= E) {
            const int4 d4 = *(const int4*)&dst[be];
            atomicAdd(&hist[d4.x >> BK2_BITS], 1);
            atomicAdd(&hist[d4.y >> BK2_BITS], 1);
            atomicAdd(&hist[d4.z >> BK2_BITS], 1);
            atomicAdd(&hist[d4.w >> BK2_BITS], 1);
        } else {
            for (long long k = be; k < E && k < be + 4; ++k)
                atomicAdd(&hist[dst[k] >> BK2_BITS], 1);
        }
    }
    __syncthreads();

    // step 2: reserve contiguous runs in padded buckets
    for (int i = t; i < nbuck; i += 256) {
        const int c = hist[i];
        hist[i] = (c > 0) ? atomicAdd(&gptr[i], c) : 0;
    }
    __syncthreads();

    // step 3: scatter into reserved runs
#pragma unroll 1
    for (int j = 0; j < PART_T / 4; ++j) {
        const long long be = e0 + ((long long)(j * 256 + t)) * 4;
        if (be + 4 <= E) {
            const int4 s4 = *(const int4*)&src[be];
            const int4 d4 = *(const int4*)&dst[be];
            int sl;
            sl = atomicAdd(&hist[d4.x >> BK2_BITS], 1);
            ebuf[sl] = (uint32)s4.x | (((uint32)d4.x & 511u) << 20);
            sl = atomicAdd(&hist[d4.y >> BK2_BITS], 1);
            ebuf[sl] = (uint32)s4.y | (((uint32)d4.y & 511u) << 20);
            sl = atomicAdd(&hist[d4.z >> BK2_BITS], 1);
            ebuf[sl] = (uint32)s4.z | (((uint32)d4.z & 511u) << 20);
            sl = atomicAdd(&hist[d4.w >> BK2_BITS], 1);
            ebuf[sl] = (uint32)s4.w | (((uint32)d4.w & 511u) << 20);
        } else {
            for (long long k = be; k < E && k < be + 4; ++k) {
                const int d = dst[k];
                const int sl = atomicAdd(&hist[d >> BK2_BITS], 1);
                ebuf[sl] = (uint32)src[k] | (((uint32)d & 511u) << 20);
            }
        }
    }
}

// ---- csrfill2: one block per bucket; LDS node-count + scan derive CSR -----
// Writes cnt[] and pos[] (= GLOBAL starts in padded esrc) for fused.
__global__ __launch_bounds__(256) void csrfill2_kernel(
    const uint32* __restrict__ ebuf, const int* __restrict__ gptr,
    int* __restrict__ pos, int* __restrict__ cnt,
    int* __restrict__ esrc, int N, int C)
{
    __shared__ int lcnt[512];
    __shared__ int lpos[512];
    __shared__ int ts[256];
    const int b = blockIdx.x;
    const int t = threadIdx.x;
    const int seg0 = b * C, seg1 = gptr[b];
    lcnt[t] = 0; lcnt[t + 256] = 0;
    __syncthreads();
    for (int i = seg0 + t; i < seg1; i += 256)
        atomicAdd(&lcnt[ebuf[i] >> 20], 1);
    __syncthreads();
    const int a0 = lcnt[2 * t], a1 = lcnt[2 * t + 1];
    ts[t] = a0 + a1;
    __syncthreads();
    for (int off = 1; off < 256; off <<= 1) {
        int x = (t >= off) ? ts[t - off] : 0;
        __syncthreads();
        ts[t] += x;
        __syncthreads();
    }
    const int pb = (t == 0) ? 0 : ts[t - 1];
    const int s0 = seg0 + pb, s1 = seg0 + pb + a0;
    lpos[2 * t] = s0; lpos[2 * t + 1] = s1;
    const int n0 = (b << BK2_BITS) + 2 * t;
    if (n0 < N)     { pos[n0] = s0;     cnt[n0] = a0; }
    if (n0 + 1 < N) { pos[n0 + 1] = s1; cnt[n0 + 1] = a1; }
    __syncthreads();
    for (int i = seg0 + t; i < seg1; i += 256) {
        const uint32 p = ebuf[i];
        const int slot = atomicAdd(&lpos[p >> 20], 1);
        esrc[slot] = (int)(p & 0xFFFFFu);
    }
}

// ===========================================================================
// Fused aggregate + ReLU(agg @ W^T + b).  bf16-gather, 4-deep load pipeline
// (round 12/14: ~118us; at L3 random-row service floor — 8-deep was null).
//   NOTE: #pragma unroll 1 on the d4 GEMM loop is load-bearing — full unroll
//   blows past 256 VGPRs and spills ~3.5 GB to scratch (rounds 2-3).
// ===========================================================================
__global__ __launch_bounds__(256) void fused_kernel_bf(
    const float* __restrict__ h, const uint16* __restrict__ hb,
    const int* __restrict__ cnt, const int* __restrict__ pos,
    const int* __restrict__ esrc,
    const float* __restrict__ Wt, const float* __restrict__ bias,
    float* __restrict__ out, int N)
{
    __shared__ float row_lds[NPB][DIM];   // 16 KB

    const int lane = threadIdx.x & 63;
    const int w    = threadIdx.x >> 6;
    const int nbase = blockIdx.x * NPB + w * 8;
    const int col2 = lane * 2;
    const uint32* __restrict__ hb32 = (const uint32*)hb;   // 64 dwords/row

#define LOADK(uX, kk) { const int s_ = __shfl(e_reg, (kk), 64); \
                        uX = hb32[((uint32)s_ << 6) | (uint32)lane]; }
#define ACC(uX) { ax += __uint_as_float(uX << 16); \
                  ay += __uint_as_float(uX & 0xffff0000u); }

#pragma unroll 1
    for (int i = 0; i < 8; ++i) {
        const int node = nbase + i;            // wave-uniform
        if (node >= N) break;
        const int deg = cnt[node];
        float ax, ay;
        if (deg == 0) {
            const float2 v = *(const float2*)&h[(size_t)node * DIM + col2];
            ax = v.x; ay = v.y;
        } else {
            const int start = pos[node];       // pos = global starts (padded)
            ax = 0.f; ay = 0.f;
            int base = 0;
#pragma unroll 1
            while (base < deg) {
                const int chunk = (deg - base < 64) ? (deg - base) : 64;
                int e_reg = 0;
                if (lane < chunk) e_reg = esrc[start + base + lane];
                int k = 0;
                if (chunk >= 4) {
                    uint32 u0, u1, u2, u3;
                    LOADK(u0, 0) LOADK(u1, 1) LOADK(u2, 2) LOADK(u3, 3)
#pragma unroll 1
                    for (; k + 8 <= chunk; k += 4) {
                        ACC(u0) LOADK(u0, k + 4)
                        ACC(u1) LOADK(u1, k + 5)
                        ACC(u2) LOADK(u2, k + 6)
                        ACC(u3) LOADK(u3, k + 7)
                    }
                    ACC(u0) ACC(u1) ACC(u2) ACC(u3)
                    k += 4;
                }
#pragma unroll 1
                for (; k < chunk; ++k) {
                    uint32 u;
                    LOADK(u, k)
                    ACC(u)
                }
                base += chunk;
            }
            const float inv = 1.0f / (float)deg;
            ax *= inv; ay *= inv;
        }
        *(float2*)&row_lds[w * 8 + i][col2] = make_float2(ax, ay);
    }
    __syncthreads();

#undef LOADK
#undef ACC

    const float2 bb = *(const float2*)&bias[col2];
    float acc0[8], acc1[8];
#pragma unroll
    for (int n = 0; n < 8; ++n) { acc0[n] = bb.x; acc1[n] = bb.y; }

#pragma unroll 1
    for (int d4 = 0; d4 < DIM; d4 += 4) {
        float4 a[8];
#pragma unroll
        for (int n = 0; n < 8; ++n)
            a[n] = *(const float4*)&row_lds[w * 8 + n][d4];   // broadcast
#pragma unroll
        for (int dd = 0; dd < 4; ++dd) {
            const float2 wt = *(const float2*)&Wt[(d4 + dd) * DIM + col2];
#pragma unroll
            for (int n = 0; n < 8; ++n) {
                const float av = dd == 0 ? a[n].x : dd == 1 ? a[n].y
                               : dd == 2 ? a[n].z : a[n].w;
                acc0[n] = fmaf(av, wt.x, acc0[n]);
                acc1[n] = fmaf(av, wt.y, acc1[n]);
            }
        }
    }

#pragma unroll
    for (int n = 0; n < 8; ++n) {
        const int node = nbase + n;
        if (node < N) {
            *(float2*)&out[(size_t)node * DIM + col2] =
                make_float2(fmaxf(acc0[n], 0.0f), fmaxf(acc1[n], 0.0f));
        }
    }
}

// ===========================================================================
// Fallback path (ws too small): per-node hist + scanA/B + direct fill + f32.
// ===========================================================================
__global__ __launch_bounds__(256) void prep_fb_kernel(
    const float* __restrict__ W, float* __restrict__ Wt,
    const int* __restrict__ dst, int* __restrict__ cnt, int E)
{
    const int bid = blockIdx.x;
    const int tid = threadIdx.x;
    if (bid < 64) {
        const int i = bid * 256 + tid;
        Wt[(i & 127) * DIM + (i >> 7)] = W[i];
    } else {
        const long long e = ((long long)(bid - 64) * 256 + tid) * 4;
        if (e + 4 <= E) {
            const int4 d4 = *(const int4*)&dst[e];
            atomicAdd(&cnt[d4.x], 1);
            atomicAdd(&cnt[d4.y], 1);
            atomicAdd(&cnt[d4.z], 1);
            atomicAdd(&cnt[d4.w], 1);
        } else {
            for (long long k = e; k < E && k < e + 4; ++k) atomicAdd(&cnt[dst[k]], 1);
        }
    }
}

__global__ __launch_bounds__(256) void scanA_kernel(const int* __restrict__ cnt,
                                                    int* __restrict__ pos,
                                                    int* __restrict__ bsum, int N)
{
    __shared__ int ts[256];
    const int t = threadIdx.x;
    const int base = blockIdx.x * SCAN_CHUNK + t * 4;
    int v[4];
    int s = 0;
#pragma unroll
    for (int k = 0; k < 4; ++k) {
        v[k] = (base + k < N) ? cnt[base + k] : 0;
        s += v[k];
    }
    ts[t] = s;
    __syncthreads();
    for (int off = 1; off < 256; off <<= 1) {
        int x = (t >= off) ? ts[t - off] : 0;
        __syncthreads();
        ts[t] += x;
        __syncthreads();
    }
    int run = (t == 0) ? 0 : ts[t - 1];
    if (t == 255) bsum[blockIdx.x] = ts[255];
#pragma unroll
    for (int k = 0; k < 4; ++k) {
        if (base + k < N) pos[base + k] = run;
        run += v[k];
    }
}

__global__ __launch_bounds__(1024) void scanB_fb_kernel(int* __restrict__ bsum, int nb)
{
    __shared__ int ts[1024];
    const int t = threadIdx.x;
    ts[t] = (t < nb) ? bsum[t] : 0;
    __syncthreads();
    for (int off = 1; off < 1024; off <<= 1) {
        int x = (t >= off) ? ts[t - off] : 0;
        __syncthreads();
        ts[t] += x;
        __syncthreads();
    }
    if (t < nb) bsum[t] = (t == 0) ? 0 : ts[t - 1];
}

__global__ __launch_bounds__(256) void fill_direct_kernel(
    const int* __restrict__ src, const int* __restrict__ dst,
    int* __restrict__ pos, const int* __restrict__ bsum,
    int* __restrict__ esrc, int E)
{
    const long long e = ((long long)blockIdx.x * 256 + threadIdx.x) * 4;
    if (e + 4 <= E) {
        const int4 s4 = *(const int4*)&src[e];
        const int4 d4 = *(const int4*)&dst[e];
        int sl;
        sl = atomicAdd(&pos[d4.x], 1); esrc[sl + bsum[d4.x >> 10]] = s4.x;
        sl = atomicAdd(&pos[d4.y], 1); esrc[sl + bsum[d4.y >> 10]] = s4.y;
        sl = atomicAdd(&pos[d4.z], 1); esrc[sl + bsum[d4.z >> 10]] = s4.z;
        sl = atomicAdd(&pos[d4.w], 1); esrc[sl + bsum[d4.w >> 10]] = s4.w;
    } else {
        for (long long k = e; k < E && k < e + 4; ++k) {
            const int d = dst[k];
            const int sl = atomicAdd(&pos[d], 1);
            esrc[sl + bsum[d >> 10]] = src[k];
        }
    }
}

__global__ __launch_bounds__(256) void fused_kernel_f32(
    const float* __restrict__ h,
    const int* __restrict__ cnt, const int* __restrict__ pos,
    const int* __restrict__ bsum, const int* __restrict__ esrc,
    const float* __restrict__ Wt, const float* __restrict__ bias,
    float* __restrict__ out, int N)
{
    __shared__ float row_lds[NPB][DIM];
    const int lane = threadIdx.x & 63;
    const int w    = threadIdx.x >> 6;
    const int nbase = blockIdx.x * NPB + w * 8;
    const int col2 = lane * 2;

#pragma unroll 1
    for (int i = 0; i < 8; ++i) {
        const int node = nbase + i;
        if (node >= N) break;
        const int deg = cnt[node];
        float ax, ay;
        if (deg == 0) {
            const float2 v = *(const float2*)&h[(size_t)node * DIM + col2];
            ax = v.x; ay = v.y;
        } else {
            const int start = pos[node] - deg + bsum[node >> 10];
            ax = 0.f; ay = 0.f;
#pragma unroll 4
            for (int k = 0; k < deg; ++k) {
                const int s = esrc[start + k];
                const float2 v = *(const float2*)&h[(size_t)s * DIM + col2];
                ax += v.x; ay += v.y;
            }
            const float inv = 1.0f / (float)deg;
            ax *= inv; ay *= inv;
        }
        *(float2*)&row_lds[w * 8 + i][col2] = make_float2(ax, ay);
    }
    __syncthreads();

    const float2 bb = *(const float2*)&bias[col2];
    float acc0[8], acc1[8];
#pragma unroll
    for (int n = 0; n < 8; ++n) { acc0[n] = bb.x; acc1[n] = bb.y; }

#pragma unroll 1
    for (int d4 = 0; d4 < DIM; d4 += 4) {
        float4 a[8];
#pragma unroll
        for (int n = 0; n < 8; ++n)
            a[n] = *(const float4*)&row_lds[w * 8 + n][d4];
#pragma unroll
        for (int dd = 0; dd < 4; ++dd) {
            const float2 wt = *(const float2*)&Wt[(d4 + dd) * DIM + col2];
#pragma unroll
            for (int n = 0; n < 8; ++n) {
                const float av = dd == 0 ? a[n].x : dd == 1 ? a[n].y
                               : dd == 2 ? a[n].z : a[n].w;
                acc0[n] = fmaf(av, wt.x, acc0[n]);
                acc1[n] = fmaf(av, wt.y, acc1[n]);
            }
        }
    }

#pragma unroll
    for (int n = 0; n < 8; ++n) {
        const int node = nbase + n;
        if (node < N) {
            *(float2*)&out[(size_t)node * DIM + col2] =
                make_float2(fmaxf(acc0[n], 0.0f), fmaxf(acc1[n], 0.0f));
        }
    }
}

// ===========================================================================
extern "C" void kernel_launch(void* const* d_in, const int* in_sizes, int n_in,
                              void* d_out, int out_size, void* d_ws, size_t ws_size,
                              hipStream_t stream)
{
    const float* h  = (const float*)d_in[0];
    const int* src  = (const int*)d_in[1];
    const int* dst  = (const int*)d_in[2];
    const float* W  = (const float*)d_in[3];
    const float* b  = (const float*)d_in[4];
    float* out = (float*)d_out;

    const int N = in_sizes[0] / DIM;
    const int E = in_sizes[1];
    const long long ND = (long long)N * DIM;
    const int nbuck = (N + (1 << BK2_BITS) - 1) >> BK2_BITS;

    // padded bucket capacity: avg * 1.25 + 256, rounded up to 256
    const int avgB = (int)(((long long)E + nbuck - 1) / nbuck);
    const int C = ((avgB + (avgB >> 2) + 256) + 255) & ~255;
    const long long padE = (long long)nbuck * C;

    // Workspace layout
    const size_t off_cnt  = 0;
    const size_t off_pos  = (size_t)N * sizeof(int);
    const size_t off_wt   = off_pos + (size_t)N * sizeof(int);
    const size_t off_gp   = off_wt + (size_t)DIM * DIM * sizeof(float);
    const size_t off_bsum = off_gp + 1024;
    const size_t off_esrc = (off_bsum + 4096 + 255) & ~(size_t)255;
    const size_t off_hb   = (off_esrc + (size_t)padE * sizeof(int) + 255) & ~(size_t)255;
    const size_t off_ebuf = (off_hb + (size_t)ND * sizeof(uint16) + 255) & ~(size_t)255;
    const size_t req_full = off_ebuf + (size_t)padE * sizeof(uint32);

    int*    cnt  = (int*)((char*)d_ws + off_cnt);
    int*    pos  = (int*)((char*)d_ws + off_pos);
    float*  Wt   = (float*)((char*)d_ws + off_wt);
    int*    gptr = (int*)((char*)d_ws + off_gp);
    int*    bsum = (int*)((char*)d_ws + off_bsum);
    int*    esrc = (int*)((char*)d_ws + off_esrc);
    uint16* hb   = (uint16*)((char*)d_ws + off_hb);
    uint32* ebuf = (uint32*)((char*)d_ws + off_ebuf);

    const int packOK   = (N <= (1 << 20)) && (nbuck <= 256);
    const int doBucket = (ws_size >= req_full && packOK) ? 1 : 0;
    const int nConv = (int)((ND / 8 + 255) / 256);
    const int nPart = (int)(((long long)E + PART_EB - 1) / PART_EB);

    if (doBucket) {
        init_kernel<<<1, 256, 0, stream>>>(gptr, nbuck, C);
        partition2_kernel<<<64 + nConv + nPart, 256, 0, stream>>>(
            W, Wt, h, hb, src, dst, gptr, ebuf, E, ND, nConv, nbuck);
        csrfill2_kernel<<<nbuck, 256, 0, stream>>>(ebuf, gptr, pos, cnt, esrc, N, C);
        fused_kernel_bf<<<(N + NPB - 1) / NPB, 256, 0, stream>>>(
            h, hb, cnt, pos, esrc, Wt, b, out, N);
    } else {
        const int nb = (N + SCAN_CHUNK - 1) / SCAN_CHUNK;
        const int nEdgeB = (int)(((long long)E / 4 + 255) / 256) + 1;
        hipMemsetAsync(cnt, 0, (size_t)N * sizeof(int), stream);
        prep_fb_kernel<<<64 + nEdgeB, 256, 0, stream>>>(W, Wt, dst, cnt, E);
        scanA_kernel<<<nb, 256, 0, stream>>>(cnt, pos, bsum, N);
        scanB_fb_kernel<<<1, 1024, 0, stream>>>(bsum, nb);
        fill_direct_kernel<<<nEdgeB, 256, 0, stream>>>(src, dst, pos, bsum, esrc, E);
        fused_kernel_f32<<<(N + NPB - 1) / NPB, 256, 0, stream>>>(
            h, cnt, pos, bsum, esrc, Wt, b, out, N);
    }
}